// Round 1
// baseline (127.912 us; speedup 1.0000x reference)
//
#include <hip/hip_runtime.h>

#define TSTEPS 600
#define NOUT   500
#define BPB    8      // batch rows per block
#define TWIN   32     // time window staged in LDS
#define RSTR   36     // padded row stride (floats): 16B-aligned, banks spread

__global__ __launch_bounds__(256)
void snn_fused(const float* __restrict__ x, const float* __restrict__ W1,
               const float* __restrict__ W2, float* __restrict__ out) {
    __shared__ float        xs[BPB * 14 * RSTR];   // 16128 B
    __shared__ float        w2s[512 * 14];         // 28672 B (zero-padded rows 500..511)
    __shared__ unsigned int evs[BPB * TSTEPS];     // 19200 B  (t<<16 | mask)
    __shared__ int          cnts[BPB];

    const int tid = threadIdx.x;
    const int b0  = blockIdx.x * BPB;

    // ---------------- phase A: LIF-1 recurrence -> spike events ----------------
    const int grp = tid >> 4;    // local batch row (0..15, active <8)
    const int c   = tid & 15;    // channel (active <14)

    float w1r[14];
    {
        const int cc = (c < 14) ? c : 13;
        #pragma unroll
        for (int j = 0; j < 14; ++j) w1r[j] = W1[cc * 14 + j];
    }
    float v1 = 0.f, cache = 0.f;
    int ne = 0;

    for (int t0 = 0; t0 < TSTEPS; t0 += TWIN) {
        const int tw = (TSTEPS - t0 >= TWIN) ? TWIN : (TSTEPS - t0);
        const int q  = tw >> 2;                 // float4s per row
        __syncthreads();                        // xs reuse guard
        const int nf4 = BPB * 14 * q;
        for (int idx = tid; idx < nf4; idx += 256) {
            int row, k;
            if (tw == TWIN) { row = idx >> 3; k = idx & 7; }
            else            { row = idx / q;  k = idx - row * q; }
            const float4 v = *(const float4*)&x[(long)(b0 * 14 + row) * TSTEPS + t0 + (k << 2)];
            *(float4*)&xs[row * RSTR + (k << 2)] = v;
        }
        __syncthreads();

        if (grp < BPB) {
            for (int tt = 0; tt < tw; tt += 4) {
                float4 xv[14];
                #pragma unroll
                for (int j = 0; j < 14; ++j)
                    xv[j] = *(const float4*)&xs[(grp * 14 + j) * RSTR + tt];
                #pragma unroll
                for (int u = 0; u < 4; ++u) {
                    float i1 = 0.5f * cache;
                    #pragma unroll
                    for (int j = 0; j < 14; ++j) {
                        const float xj = (u == 0) ? xv[j].x : (u == 1) ? xv[j].y
                                       : (u == 2) ? xv[j].z : xv[j].w;
                        i1 += xj * w1r[j];
                    }
                    v1 = v1 + (i1 - v1) * 0.5f;          // LIF charge (tau=2)
                    const bool s = (c < 14) && (v1 >= 7.0f);
                    const unsigned long long bal = __ballot(s);
                    const unsigned m = ((unsigned)(bal >> (tid & 48))) & 0x3FFFu;
                    if (s) v1 = 0.f;                      // hard reset
                    cache = s ? 1.f : 0.f;                // feedback for next step
                    if (c == 0 && m)
                        evs[grp * TSTEPS + ne++] = ((unsigned)(t0 + tt + u) << 16) | m;
                }
            }
        }
    }
    if (grp < BPB && c == 0) cnts[grp] = ne;

    // ---------------- W2 -> LDS (zero-padded) ----------------
    for (int i = tid; i < 512 * 14; i += 256)
        w2s[i] = (i < NOUT * 14) ? W2[i] : 0.f;
    __syncthreads();   // covers evs/cnts/w2s

    // ---------------- phase B: event-driven LIF-2 ----------------
    const int sub  = tid >> 5;         // local batch row (0..7)
    const int lane = tid & 31;         // output slice: o = lane + 32*r
    const int nev  = cnts[sub];
    float v2[16];
    #pragma unroll
    for (int r = 0; r < 16; ++r) v2[r] = 0.f;
    int tprev = -1;
    const unsigned int* ev = &evs[sub * TSTEPS];

    for (int e = 0; e < nev; ++e) {
        const unsigned evv = ev[e];
        const int t = (int)(evv >> 16);
        unsigned mm = evv & 0x3FFFu;
        const int gap = t - tprev - 1;
        if (gap > 0) {                       // exact run of pure-decay steps
            #pragma unroll
            for (int r = 0; r < 16; ++r) v2[r] = ldexpf(v2[r], -gap);
        }
        float i2[16];
        #pragma unroll
        for (int r = 0; r < 16; ++r) i2[r] = 0.f;
        while (mm) {                         // sum active W2 columns
            const int cc = __builtin_ctz(mm);
            mm &= mm - 1;
            #pragma unroll
            for (int r = 0; r < 16; ++r) i2[r] += w2s[(lane + (r << 5)) * 14 + cc];
        }
        #pragma unroll
        for (int r = 0; r < 16; ++r) {
            const float v = v2[r] + (i2[r] - v2[r]) * 0.5f;   // charge
            v2[r] = (v >= 7.0f) ? 0.f : v;                    // reset
        }
        tprev = t;
    }
    {
        const int gap = (TSTEPS - 1) - tprev;
        if (gap > 0) {
            #pragma unroll
            for (int r = 0; r < 16; ++r) v2[r] = ldexpf(v2[r], -gap);
        }
    }
    #pragma unroll
    for (int r = 0; r < 16; ++r) {
        const int o = lane + (r << 5);
        if (o < NOUT) out[(long)(b0 + sub) * NOUT + o] = expf(v2[r]);
    }
}

extern "C" void kernel_launch(void* const* d_in, const int* in_sizes, int n_in,
                              void* d_out, int out_size, void* d_ws, size_t ws_size,
                              hipStream_t stream) {
    const float* x  = (const float*)d_in[0];
    const float* W1 = (const float*)d_in[1];
    const float* W2 = (const float*)d_in[2];
    float* out = (float*)d_out;
    const int B = in_sizes[0] / (14 * TSTEPS);   // 4096
    snn_fused<<<B / BPB, 256, 0, stream>>>(x, W1, W2, out);
}

// Round 2
// 55.839 us; speedup vs baseline: 2.2907x; 2.2907x over previous
//
#include <hip/hip_runtime.h>
#include <math.h>

#define T      600
#define C      14
#define NOUT   500
#define R      8          // batch rows per block
#define W      128        // time window per GEMM/recurrence phase
#define DSTR   132        // padded t-stride for D in LDS (floats)
#define EVCAP  256        // max recorded events per row

__global__ __launch_bounds__(256, 2)
void snn_v2(const float* __restrict__ x, const float* __restrict__ W1,
            const float* __restrict__ W2, float* __restrict__ out) {
    __shared__ float    ds[R * C * DSTR];    // 0.5 * D window   59136 B
    __shared__ unsigned evs[R * EVCAP];      // (t<<4)|c          8192 B
    __shared__ int      ecnt[R];

    const int tid = threadIdx.x;
    const int b0  = blockIdx.x * R;

    if (tid < R) ecnt[tid] = 0;

    // ---- recurrence lane mapping: 8 rows x 16 channel-slots, pair-mirrored ----
    const int  rr   = tid >> 5;              // row 0..7 (row fully inside one wave)
    const int  cc   = (tid >> 1) & 15;       // channel slot (even/odd lanes mirror)
    const int  ce   = (cc < C) ? cc : (C - 1);   // mirror slot 14,15 onto 13
    const bool aact = ((tid & 1) == 0) && (cc < C);  // append-eligible lane
    float v1 = 0.f;

    // ---- GEMM task mapping: one thread = (row, 4-step quad) ----
    const int gr  = tid >> 5;
    const int gt4 = tid & 31;

    for (int t0 = 0; t0 < T; t0 += W) {
        const int wlen = (T - t0 < W) ? (T - t0) : W;   // 128,128,128,128,88
        __syncthreads();                     // ds free to overwrite

        // ================= phase 1: D window (parallel GEMM) =================
        if (gt4 * 4 < wlen) {
            const int tt = t0 + gt4 * 4;
            float4 xv[C];
            #pragma unroll
            for (int j = 0; j < C; ++j)
                xv[j] = *(const float4*)&x[((long)(b0 + gr) * C + j) * T + tt];
            #pragma unroll
            for (int c = 0; c < C; ++c) {
                float ax = 0.f, ay = 0.f, az = 0.f, aw = 0.f;
                #pragma unroll
                for (int j = 0; j < C; ++j) {
                    const float w = W1[c * C + j];       // wave-uniform -> s_load
                    ax = fmaf(xv[j].x, w, ax);
                    ay = fmaf(xv[j].y, w, ay);
                    az = fmaf(xv[j].z, w, az);
                    aw = fmaf(xv[j].w, w, aw);
                }
                float4 st = make_float4(0.5f * ax, 0.5f * ay, 0.5f * az, 0.5f * aw);
                *(float4*)&ds[(gr * C + c) * DSTR + gt4 * 4] = st;
            }
        }
        __syncthreads();

        // ================= phase 2: LIF-1 recurrence (short chain) ===========
        {
            const float* dp = &ds[(rr * C + ce) * DSTR];
            float4 hd = *(const float4*)&dp[0];
            for (int q = 0; q < wlen; q += 4) {
                float4 nhd;
                if (q + 4 < wlen) nhd = *(const float4*)&dp[q + 4];  // prefetch
                #pragma unroll
                for (int u = 0; u < 4; ++u) {
                    const float h = (u == 0) ? hd.x : (u == 1) ? hd.y
                                  : (u == 2) ? hd.z : hd.w;
                    v1 = fmaf(v1, 0.5f, h);              // v = 0.5 v + 0.5 d
                    if (__ballot(v1 >= 7.0f)) {          // rare wave-uniform path
                        const bool s = (v1 >= 7.0f);
                        if (s) v1 = 0.5f;                // reset + exact feedback fold
                        if (s && aact) {
                            const int idx = atomicAdd(&ecnt[rr], 1);
                            if (idx < EVCAP)
                                evs[rr * EVCAP + idx] =
                                    ((unsigned)(t0 + q + u) << 4) | (unsigned)cc;
                        }
                    }
                }
                hd = nhd;
            }
        }
    }
    __syncthreads();   // evs/ecnt complete

    // ================= phase 3: event-driven LIF-2 + exp =====================
    const int lane = tid & 31;               // row rr, outputs o = lane + 32k
    const int nev  = min(ecnt[rr], EVCAP);
    const unsigned* ev = &evs[rr * EVCAP];

    float v2[16];
    #pragma unroll
    for (int k = 0; k < 16; ++k) v2[k] = 0.f;
    int tprev = -1;

    int e = 0;
    while (e < nev) {
        const int t = (int)(ev[e] >> 4);
        float i2[16];
        #pragma unroll
        for (int k = 0; k < 16; ++k) i2[k] = 0.f;
        do {                                  // merge all channels firing at t
            const int c = (int)(ev[e] & 15);
            #pragma unroll
            for (int k = 0; k < 16; ++k) {
                const int o = lane + (k << 5);
                if (o < NOUT) i2[k] += W2[o * C + c];
            }
            ++e;
        } while (e < nev && (int)(ev[e] >> 4) == t);

        const int gap = t - tprev - 1;
        if (gap > 0) {
            #pragma unroll
            for (int k = 0; k < 16; ++k) v2[k] = ldexpf(v2[k], -gap);
        }
        #pragma unroll
        for (int k = 0; k < 16; ++k) {
            const float v = v2[k] + (i2[k] - v2[k]) * 0.5f;   // charge (ref order)
            v2[k] = (v >= 7.0f) ? 0.f : v;                    // hard reset
        }
        tprev = t;
    }
    {
        const int gap = (T - 1) - tprev;
        if (gap > 0) {
            #pragma unroll
            for (int k = 0; k < 16; ++k) v2[k] = ldexpf(v2[k], -gap);
        }
    }
    #pragma unroll
    for (int k = 0; k < 16; ++k) {
        const int o = lane + (k << 5);
        if (o < NOUT) out[(long)(b0 + rr) * NOUT + o] = expf(v2[k]);
    }
}

extern "C" void kernel_launch(void* const* d_in, const int* in_sizes, int n_in,
                              void* d_out, int out_size, void* d_ws, size_t ws_size,
                              hipStream_t stream) {
    const float* x  = (const float*)d_in[0];
    const float* W1 = (const float*)d_in[1];
    const float* W2 = (const float*)d_in[2];
    float* o = (float*)d_out;
    const int B = in_sizes[0] / (C * T);     // 4096
    snn_v2<<<B / R, 256, 0, stream>>>(x, W1, W2, o);
}

// Round 3
// 44.666 us; speedup vs baseline: 2.8638x; 1.2501x over previous
//
#include <hip/hip_runtime.h>
#include <math.h>

#define T      600
#define C      14
#define NOUT   500
#define R      4          // batch rows per block
#define W      128        // time window
#define DSTR   132        // padded t-stride for ds (floats)
#define EVCAP  256        // max events per row

__global__ __launch_bounds__(128, 2)
void snn_v3(const float* __restrict__ x, const float* __restrict__ W1,
            const float* __restrict__ W2, float* __restrict__ out) {
    __shared__ float    ds[R * C * DSTR];    // 0.5*D window, 29568 B
    __shared__ unsigned evs[R * EVCAP];      // (t<<4)|c, 4096 B
    __shared__ int      ecnt[R];

    const int tid = threadIdx.x;
    const int b0  = blockIdx.x * R;
    if (tid < R) ecnt[tid] = 0;

    const int  rr   = tid >> 5;              // row 0..3 (GEMM + recurrence + out)
    const int  qq   = tid & 31;              // GEMM t-quad
    const int  cc   = (tid >> 1) & 15;       // recurrence channel slot (pair-mirrored)
    const int  ce   = (cc < C) ? cc : (C - 1);
    const bool aact = ((tid & 1) == 0) && (cc < C);

    // ---- initial prefetch: window 0 into registers ----
    float4 xv[C];
    #pragma unroll
    for (int j = 0; j < C; ++j)
        xv[j] = *(const float4*)&x[((long)(b0 + rr) * C + j) * T + qq * 4];

    float v1 = 0.f;

    for (int t0 = 0; t0 < T; t0 += W) {
        const int wlen = (T - t0 < W) ? (T - t0) : W;   // 128 x4, then 88
        __syncthreads();                     // prev recurrence done reading ds

        // ===== GEMM from prefetched regs (no global access here) =====
        if (qq * 4 < wlen) {
            #pragma unroll
            for (int c = 0; c < C; ++c) {
                float ax = 0.f, ay = 0.f, az = 0.f, aw = 0.f;
                #pragma unroll
                for (int j = 0; j < C; ++j) {
                    const float w = 0.5f * W1[c * C + j];   // exact pow2 fold
                    ax = fmaf(xv[j].x, w, ax);
                    ay = fmaf(xv[j].y, w, ay);
                    az = fmaf(xv[j].z, w, az);
                    aw = fmaf(xv[j].w, w, aw);
                }
                *(float4*)&ds[(rr * C + c) * DSTR + qq * 4] = make_float4(ax, ay, az, aw);
            }
        }

        // ===== issue prefetch for next window (hides under recurrence) =====
        {
            const int tn = t0 + W + qq * 4;
            if (tn < T) {
                #pragma unroll
                for (int j = 0; j < C; ++j)
                    xv[j] = *(const float4*)&x[((long)(b0 + rr) * C + j) * T + tn];
            }
        }
        __syncthreads();                     // ds ready

        // ===== LIF-1 recurrence: speculative 4-step batches =====
        const float* dp = &ds[(rr * C + ce) * DSTR];
        for (int q = 0; q < wlen; q += 4) {
            const float4 hd = *(const float4*)&dp[q];
            const float a  = fmaf(v1, 0.5f, hd.x);
            const float b  = fmaf(a,  0.5f, hd.y);
            const float c2 = fmaf(b,  0.5f, hd.z);
            const float d  = fmaf(c2, 0.5f, hd.w);
            const float m  = fmaxf(fmaxf(a, b), fmaxf(c2, d));
            if (__builtin_expect(__ballot(m >= 7.0f) != 0ull, 0)) {
                // exact slow path: redo the 4 steps with reset + event append
                float vv = v1;
                #pragma unroll
                for (int u = 0; u < 4; ++u) {
                    const float h = (u == 0) ? hd.x : (u == 1) ? hd.y
                                  : (u == 2) ? hd.z : hd.w;
                    vv = fmaf(vv, 0.5f, h);
                    if (vv >= 7.0f) {
                        vv = 0.5f;           // reset + exact feedback fold
                        if (aact) {
                            const int idx = atomicAdd(&ecnt[rr], 1);
                            if (idx < EVCAP)
                                evs[rr * EVCAP + idx] =
                                    ((unsigned)(t0 + q + u) << 4) | (unsigned)cc;
                        }
                    }
                }
                v1 = vv;
            } else {
                v1 = d;                      // no spike in batch: bitwise exact
            }
        }
    }
    __syncthreads();

    // ===== event-driven LIF-2 + exp =====
    const int lane = tid & 31;               // outputs o = lane + 32k for row rr
    const int nev  = min(ecnt[rr], EVCAP);
    const unsigned* ev = &evs[rr * EVCAP];

    float v2[16];
    #pragma unroll
    for (int k = 0; k < 16; ++k) v2[k] = 0.f;
    int tprev = -1;

    int e = 0;
    while (e < nev) {
        const int t = (int)(ev[e] >> 4);
        float i2[16];
        #pragma unroll
        for (int k = 0; k < 16; ++k) i2[k] = 0.f;
        do {                                 // merge all channels firing at t
            const int c = (int)(ev[e] & 15);
            #pragma unroll
            for (int k = 0; k < 16; ++k) {
                const int o = lane + (k << 5);
                if (o < NOUT) i2[k] += W2[o * C + c];
            }
            ++e;
        } while (e < nev && (int)(ev[e] >> 4) == t);

        const int gap = t - tprev - 1;
        if (gap > 0) {
            #pragma unroll
            for (int k = 0; k < 16; ++k) v2[k] = ldexpf(v2[k], -gap);
        }
        #pragma unroll
        for (int k = 0; k < 16; ++k) {
            const float v = v2[k] + (i2[k] - v2[k]) * 0.5f;   // charge (ref order)
            v2[k] = (v >= 7.0f) ? 0.f : v;                    // hard reset
        }
        tprev = t;
    }
    {
        const int gap = (T - 1) - tprev;
        if (gap > 0) {
            #pragma unroll
            for (int k = 0; k < 16; ++k) v2[k] = ldexpf(v2[k], -gap);
        }
    }
    #pragma unroll
    for (int k = 0; k < 16; ++k) {
        const int o = lane + (k << 5);
        if (o < NOUT) out[(long)(b0 + rr) * NOUT + o] = expf(v2[k]);
    }
}

extern "C" void kernel_launch(void* const* d_in, const int* in_sizes, int n_in,
                              void* d_out, int out_size, void* d_ws, size_t ws_size,
                              hipStream_t stream) {
    const float* x  = (const float*)d_in[0];
    const float* W1 = (const float*)d_in[1];
    const float* W2 = (const float*)d_in[2];
    float* o = (float*)d_out;
    const int B = in_sizes[0] / (C * T);     // 4096
    snn_v3<<<B / R, 128, 0, stream>>>(x, W1, W2, o);
}